// Round 4
// baseline (1312.678 us; speedup 1.0000x reference)
//
#include <hip/hip_runtime.h>
#include <hip/hip_bf16.h>
#include <stdint.h>

typedef __hip_bfloat16 bf16;
typedef float f32x4 __attribute__((ext_vector_type(4)));
typedef __bf16 bf16x8 __attribute__((ext_vector_type(8)));

__device__ __forceinline__ float b2f(bf16 v) { return __bfloat162float(v); }
__device__ __forceinline__ bf16 f2b(float v) { return __float2bfloat16(v); }
__device__ __forceinline__ unsigned short f2bu(float f) {
  unsigned u = __float_as_uint(f);
  unsigned r = u + 0x7fffu + ((u >> 16) & 1u);
  return (unsigned short)(r >> 16);
}

// B=4, N=4096, D_POINTS=512, D_MODEL=256, K=16

// compare-exchange on u64 keys: min -> a, max -> b (1 cmp + 4 cndmask, no arrays)
#define CE64(a, b)                                            \
  do {                                                        \
    bool c_ = (b) < (a);                                      \
    unsigned long long lo_ = c_ ? (b) : (a);                  \
    unsigned long long hi_ = c_ ? (a) : (b);                  \
    (a) = lo_; (b) = hi_;                                     \
  } while (0)

// ascending / descending compare-exchange, and min-only (3 ops)
#define CEA(x, y) CE64(x, y)
#define CED(x, y) CE64(y, x)
#define MIN64(x, y)                                           \
  do {                                                        \
    (x) = (y) < (x) ? (y) : (x);                              \
  } while (0)

// ---------------- pack xyz -> float4(x,y,z,sq) ----------------
__global__ __launch_bounds__(256) void pack_pts(const float* __restrict__ xyz,
                                                float4* __restrict__ pts) {
  int i = blockIdx.x * 256 + threadIdx.x;   // 0..16383
  float x = xyz[i * 3 + 0];
  float y = xyz[i * 3 + 1];
  float z = xyz[i * 3 + 2];
  float sq = __fadd_rn(__fadd_rn(__fmul_rn(x, x), __fmul_rn(y, y)), __fmul_rn(z, z));
  pts[i] = make_float4(x, y, z, sq);
}

// ---------------- knn partial: 2048 blocks; block=(group g, range r) ----------------
__global__ __launch_bounds__(256) void knn_partial(const float4* __restrict__ pts,
                                                   unsigned long long* __restrict__ keys) {
  __shared__ __align__(16) float4 cs[512];
  __shared__ __align__(16) float4 qs[64];

  int tid = threadIdx.x;
  int g = blockIdx.x >> 3;          // query group 0..255 (64 queries each)
  int r = blockIdx.x & 7;           // candidate range (512 candidates)
  int batch = g >> 6;
  const float4* pp = pts + batch * 4096;
  int cb = r * 512;

  cs[tid] = pp[cb + tid];
  cs[256 + tid] = pp[cb + 256 + tid];
  if (tid < 64) qs[tid] = pp[(g & 63) * 64 + tid];
  __syncthreads();

  int wave = tid >> 6, lq = tid & 63;
  float4 Q = qs[lq];
  int mbase = cb + wave * 128;

  unsigned long long a[16];
#pragma unroll
  for (int i = 0; i < 16; ++i) a[i] = ~0ull;

#pragma unroll 2
  for (int tb = 0; tb < 16; ++tb) {
    unsigned long long c[8];
#pragma unroll
    for (int j = 0; j < 8; ++j) {
      float4 P = cs[wave * 128 + tb * 8 + j];
      float dot = __fadd_rn(__fadd_rn(__fmul_rn(Q.x, P.x), __fmul_rn(Q.y, P.y)),
                            __fmul_rn(Q.z, P.z));
      float d = __fsub_rn(__fadd_rn(Q.w, P.w), __fmul_rn(2.0f, dot));
      unsigned u = __float_as_uint(d);
      u ^= (unsigned)((int)u >> 31) | 0x80000000u;   // monotonic float bits
      c[j] = ((unsigned long long)u << 32) | (unsigned)(mbase + tb * 8 + j);
    }

    // bitonic sort8 ascending: c[0] <= ... <= c[7]
    CEA(c[0], c[1]); CED(c[2], c[3]); CEA(c[4], c[5]); CED(c[6], c[7]);
    CEA(c[0], c[2]); CEA(c[1], c[3]); CED(c[4], c[6]); CED(c[5], c[7]);
    CEA(c[0], c[1]); CEA(c[2], c[3]); CED(c[4], c[5]); CED(c[6], c[7]);
    CEA(c[0], c[4]); CEA(c[1], c[5]); CEA(c[2], c[6]); CEA(c[3], c[7]);
    CEA(c[0], c[2]); CEA(c[1], c[3]); CEA(c[4], c[6]); CEA(c[5], c[7]);
    CEA(c[0], c[1]); CEA(c[2], c[3]); CEA(c[4], c[5]); CEA(c[6], c[7]);

    // lower-16 of merge(a asc16, c asc8): positions 8..15 take min with reversed c
    MIN64(a[8],  c[7]); MIN64(a[9],  c[6]); MIN64(a[10], c[5]); MIN64(a[11], c[4]);
    MIN64(a[12], c[3]); MIN64(a[13], c[2]); MIN64(a[14], c[1]); MIN64(a[15], c[0]);

    // bitonic clean-16 (result is bitonic): distances 8,4,2,1, all ascending
    CEA(a[0], a[8]);  CEA(a[1], a[9]);  CEA(a[2], a[10]); CEA(a[3], a[11]);
    CEA(a[4], a[12]); CEA(a[5], a[13]); CEA(a[6], a[14]); CEA(a[7], a[15]);
    CEA(a[0], a[4]);  CEA(a[1], a[5]);  CEA(a[2], a[6]);  CEA(a[3], a[7]);
    CEA(a[8], a[12]); CEA(a[9], a[13]); CEA(a[10], a[14]); CEA(a[11], a[15]);
    CEA(a[0], a[2]);  CEA(a[1], a[3]);  CEA(a[4], a[6]);  CEA(a[5], a[7]);
    CEA(a[8], a[10]); CEA(a[9], a[11]); CEA(a[12], a[14]); CEA(a[13], a[15]);
    CEA(a[0], a[1]);  CEA(a[2], a[3]);  CEA(a[4], a[5]);  CEA(a[6], a[7]);
    CEA(a[8], a[9]);  CEA(a[10], a[11]); CEA(a[12], a[13]); CEA(a[14], a[15]);
  }

  int rw = r * 4 + wave;            // 0..31
  int q = g * 64 + lq;
  unsigned long long* o = keys + (size_t)(rw * 16) * 16384 + q;
#pragma unroll
  for (int j = 0; j < 16; ++j) o[(size_t)j * 16384] = a[j];
}

// ---------------- knn merge: 32 sorted lists -> final 16, thread per query ----------------
__global__ __launch_bounds__(256) void knn_merge(const unsigned long long* __restrict__ keys,
                                                 int* __restrict__ gidx) {
  int q = blockIdx.x * 256 + threadIdx.x;   // 0..16383
  const unsigned long long* kq = keys + q;

#define LOADL(rw)                                   \
  unsigned long long l0 = kq[((rw) * 16 + 0) * 16384],  l1 = kq[((rw) * 16 + 1) * 16384],  \
                     l2 = kq[((rw) * 16 + 2) * 16384],  l3 = kq[((rw) * 16 + 3) * 16384],  \
                     l4 = kq[((rw) * 16 + 4) * 16384],  l5 = kq[((rw) * 16 + 5) * 16384],  \
                     l6 = kq[((rw) * 16 + 6) * 16384],  l7 = kq[((rw) * 16 + 7) * 16384],  \
                     l8 = kq[((rw) * 16 + 8) * 16384],  l9 = kq[((rw) * 16 + 9) * 16384],  \
                     l10 = kq[((rw) * 16 + 10) * 16384], l11 = kq[((rw) * 16 + 11) * 16384], \
                     l12 = kq[((rw) * 16 + 12) * 16384], l13 = kq[((rw) * 16 + 13) * 16384], \
                     l14 = kq[((rw) * 16 + 14) * 16384], l15 = kq[((rw) * 16 + 15) * 16384]

  unsigned long long a0 = kq[0],           a1 = kq[16384],      a2 = kq[2 * 16384],
                     a3 = kq[3 * 16384],   a4 = kq[4 * 16384],  a5 = kq[5 * 16384],
                     a6 = kq[6 * 16384],   a7 = kq[7 * 16384],  a8 = kq[8 * 16384],
                     a9 = kq[9 * 16384],   a10 = kq[10 * 16384], a11 = kq[11 * 16384],
                     a12 = kq[12 * 16384], a13 = kq[13 * 16384], a14 = kq[14 * 16384],
                     a15 = kq[15 * 16384];

  for (int rw = 1; rw < 32; ++rw) {
    LOADL(rw);
    // lower half of bitonic merge of (a asc ++ l desc): min(a_i, l_{15-i}) -> bitonic
    a0 = a0 < l15 ? a0 : l15;   a1 = a1 < l14 ? a1 : l14;
    a2 = a2 < l13 ? a2 : l13;   a3 = a3 < l12 ? a3 : l12;
    a4 = a4 < l11 ? a4 : l11;   a5 = a5 < l10 ? a5 : l10;
    a6 = a6 < l9 ? a6 : l9;     a7 = a7 < l8 ? a7 : l8;
    a8 = a8 < l7 ? a8 : l7;     a9 = a9 < l6 ? a9 : l6;
    a10 = a10 < l5 ? a10 : l5;  a11 = a11 < l4 ? a11 : l4;
    a12 = a12 < l3 ? a12 : l3;  a13 = a13 < l2 ? a13 : l2;
    a14 = a14 < l1 ? a14 : l1;  a15 = a15 < l0 ? a15 : l0;
    // bitonic sort of 16 bitonic elements: stages 8,4,2,1
    CE64(a0, a8);  CE64(a1, a9);  CE64(a2, a10); CE64(a3, a11);
    CE64(a4, a12); CE64(a5, a13); CE64(a6, a14); CE64(a7, a15);
    CE64(a0, a4);  CE64(a1, a5);  CE64(a2, a6);  CE64(a3, a7);
    CE64(a8, a12); CE64(a9, a13); CE64(a10, a14); CE64(a11, a15);
    CE64(a0, a2);  CE64(a1, a3);  CE64(a4, a6);  CE64(a5, a7);
    CE64(a8, a10); CE64(a9, a11); CE64(a12, a14); CE64(a13, a15);
    CE64(a0, a1);  CE64(a2, a3);  CE64(a4, a5);  CE64(a6, a7);
    CE64(a8, a9);  CE64(a10, a11); CE64(a12, a13); CE64(a14, a15);
  }
#undef LOADL

  int base = (q >> 12) << 12;   // batch*4096
  int* o = gidx + (size_t)q * 16;
  o[0] = base + (int)(a0 & 0xffffffffu);   o[1] = base + (int)(a1 & 0xffffffffu);
  o[2] = base + (int)(a2 & 0xffffffffu);   o[3] = base + (int)(a3 & 0xffffffffu);
  o[4] = base + (int)(a4 & 0xffffffffu);   o[5] = base + (int)(a5 & 0xffffffffu);
  o[6] = base + (int)(a6 & 0xffffffffu);   o[7] = base + (int)(a7 & 0xffffffffu);
  o[8] = base + (int)(a8 & 0xffffffffu);   o[9] = base + (int)(a9 & 0xffffffffu);
  o[10] = base + (int)(a10 & 0xffffffffu); o[11] = base + (int)(a11 & 0xffffffffu);
  o[12] = base + (int)(a12 & 0xffffffffu); o[13] = base + (int)(a13 & 0xffffffffu);
  o[14] = base + (int)(a14 & 0xffffffffu); o[15] = base + (int)(a15 & 0xffffffffu);
}

// ---------------- weight transpose + f32->bf16 ----------------
__global__ __launch_bounds__(256) void transpose_k(const float* __restrict__ src,
                                                   bf16* __restrict__ dst,
                                                   int R, int C) {
  int i = blockIdx.x * 256 + threadIdx.x;
  if (i < R * C) {
    int r = i / C, c = i - r * C;
    dst[c * R + r] = f2b(src[i]);
  }
}

// ---------------- hidden = relu(rel @ Wd1 + bd1) ----------------
__global__ __launch_bounds__(256) void hidden_kernel(const float* __restrict__ xyz,
                                                     const int* __restrict__ gidx,
                                                     const float* __restrict__ Wd1,
                                                     const float* __restrict__ bd1,
                                                     bf16* __restrict__ hidden) {
  __shared__ float rel[16][3];
  int q = blockIdx.x;
  int tid = threadIdx.x;
  if (tid < 16) {
    int g = gidx[q * 16 + tid];
    rel[tid][0] = xyz[(size_t)q * 3 + 0] - xyz[(size_t)g * 3 + 0];
    rel[tid][1] = xyz[(size_t)q * 3 + 1] - xyz[(size_t)g * 3 + 1];
    rel[tid][2] = xyz[(size_t)q * 3 + 2] - xyz[(size_t)g * 3 + 2];
  }
  __syncthreads();
  float w0 = Wd1[tid], w1 = Wd1[256 + tid], w2 = Wd1[512 + tid];
  float bb = bd1[tid];
#pragma unroll
  for (int j = 0; j < 16; ++j) {
    float v = rel[j][0] * w0 + rel[j][1] * w1 + rel[j][2] * w2 + bb;
    v = fmaxf(v, 0.0f);
    hidden[((size_t)q * 16 + j) * 256 + tid] = f2b(v);
  }
}

// ---------------- fused pos/attn chain ----------------
// Per block: 64 rows (4 queries). LDS-resident A-tile, 3 chained GEMMs
// (Wd2, Wg1, Wg2), epilogues in-register. vp takes a CONTROLLED round trip
// through global (vpbuf) instead of 32 persistent VGPRs — keeps peak register
// demand at acc(64)+transient(~45) < 128, avoiding compiler scratch spills
// (round-3: 1.08 GB of spill writes at 128 VGPRs with vp held in registers).
__global__ __launch_bounds__(256) void fused_pt(
    const bf16* __restrict__ hidden,   // [262144,256] relu(rel@Wd1+bd1)
    const bf16* __restrict__ wd2t, const float* __restrict__ bd2,
    const bf16* __restrict__ wg1t, const float* __restrict__ bg1,
    const bf16* __restrict__ wg2t, const float* __restrict__ bg2,
    const bf16* __restrict__ qbuf, const bf16* __restrict__ kbuf,
    const bf16* __restrict__ vbuf, const int* __restrict__ gidx,
    bf16* __restrict__ vpbuf,          // [262144,256] v+pos round trip
    float* __restrict__ attn_out,      // [262144,256] f32
    bf16* __restrict__ respre) {       // [16384,256]
  __shared__ __align__(16) unsigned short Ht[64 * 264];   // A tile, stride 264
  __shared__ __align__(16) unsigned short Bs[256 * 72];   // B k-chunk, stride 72

  int m0 = blockIdx.x * 64;
  int tid = threadIdx.x;
  int wave = tid >> 6, lane = tid & 63;
  int wr = wave >> 1, wc = wave & 1;          // 2x2 waves: 32-row x 128-col tiles
  int lm = lane & 15, lqd = lane >> 4;

  // stage hidden tile: 64x256 bf16 = 2048 int4, 8 per thread
#pragma unroll
  for (int i = 0; i < 8; ++i) {
    int flat = i * 256 + tid;
    int row = flat >> 5;          // 32 int4 per row
    int u = flat & 31;
    int4 hv = *reinterpret_cast<const int4*>(hidden + (size_t)(m0 + row) * 256 + u * 8);
    *reinterpret_cast<int4*>(&Ht[row * 264 + u * 8]) = hv;
  }

  f32x4 acc[2][8];
#pragma unroll
  for (int mi = 0; mi < 2; ++mi)
#pragma unroll
    for (int ni = 0; ni < 8; ++ni) acc[mi][ni] = (f32x4){0.f, 0.f, 0.f, 0.f};

  // GEMM over K=256 in 64-wide chunks; A from Ht (LDS-resident), B streamed.
#define GEMM_LOOP(BTP)                                                          \
  for (int k0 = 0; k0 < 256; k0 += 64) {                                        \
    int4 breg[8];                                                               \
    _Pragma("unroll")                                                           \
    for (int i = 0; i < 8; ++i) {                                               \
      int flat = i * 256 + tid;                                                 \
      int row = flat >> 3;                                                      \
      int u = flat & 7;                                                         \
      breg[i] = *reinterpret_cast<const int4*>((BTP) + (size_t)row * 256 + k0 + u * 8); \
    }                                                                           \
    __syncthreads();                                                            \
    _Pragma("unroll")                                                           \
    for (int i = 0; i < 8; ++i) {                                               \
      int flat = i * 256 + tid;                                                 \
      int row = flat >> 3;                                                      \
      int u = flat & 7;                                                         \
      *reinterpret_cast<int4*>(&Bs[row * 72 + u * 8]) = breg[i];                \
    }                                                                           \
    __syncthreads();                                                            \
    _Pragma("unroll")                                                           \
    for (int ks = 0; ks < 2; ++ks) {                                            \
      bf16x8 af[2], bfr[8];                                                     \
      _Pragma("unroll")                                                         \
      for (int mi = 0; mi < 2; ++mi)                                            \
        af[mi] = *reinterpret_cast<const bf16x8*>(                              \
            &Ht[(wr * 32 + mi * 16 + lm) * 264 + k0 + ks * 32 + lqd * 8]);      \
      _Pragma("unroll")                                                         \
      for (int ni = 0; ni < 8; ++ni)                                            \
        bfr[ni] = *reinterpret_cast<const bf16x8*>(                             \
            &Bs[(wc * 128 + ni * 16 + lm) * 72 + ks * 32 + lqd * 8]);           \
      _Pragma("unroll")                                                         \
      for (int mi = 0; mi < 2; ++mi)                                            \
        _Pragma("unroll")                                                       \
        for (int ni = 0; ni < 8; ++ni)                                          \
          acc[mi][ni] = __builtin_amdgcn_mfma_f32_16x16x32_bf16(                \
              af[mi], bfr[ni], acc[mi][ni], 0, 0, 0);                           \
    }                                                                           \
  }

  // ---- GEMM1: pos = hidden @ Wd2^T ----
  GEMM_LOOP(wd2t)

  // ---- epilogue 1: h = q - k + pos -> Ht;  vp = v + pos -> vpbuf (global) ----
  __syncthreads();
#pragma unroll
  for (int mi = 0; mi < 2; ++mi) {
    int mtile = m0 + wr * 32 + mi * 16;    // 16 rows = one query
    int qrow = mtile >> 4;
    int gi[4];
#pragma unroll
    for (int r = 0; r < 4; ++r) gi[r] = gidx[mtile + lqd * 4 + r];
#pragma unroll
    for (int ni = 0; ni < 8; ++ni) {
      int n = wc * 128 + ni * 16 + lm;
      float qv = b2f(qbuf[(size_t)qrow * 256 + n]);
      float bdv = bd2[n];
#pragma unroll
      for (int r = 0; r < 4; ++r) {
        float pos = acc[mi][ni][r] + bdv;
        float kv = b2f(kbuf[(size_t)gi[r] * 256 + n]);
        float vv = b2f(vbuf[(size_t)gi[r] * 256 + n]);
        size_t m = (size_t)(mtile + lqd * 4 + r);
        Ht[(wr * 32 + mi * 16 + lqd * 4 + r) * 264 + n] = f2bu(qv - kv + pos);
        vpbuf[m * 256 + n] = f2b(vv + pos);
      }
    }
  }
  __syncthreads();

#pragma unroll
  for (int mi = 0; mi < 2; ++mi)
#pragma unroll
    for (int ni = 0; ni < 8; ++ni) acc[mi][ni] = (f32x4){0.f, 0.f, 0.f, 0.f};

  // ---- GEMM2: t = relu(h @ Wg1^T + bg1) ----
  GEMM_LOOP(wg1t)

  __syncthreads();
#pragma unroll
  for (int mi = 0; mi < 2; ++mi)
#pragma unroll
    for (int ni = 0; ni < 8; ++ni) {
      int n = wc * 128 + ni * 16 + lm;
      float bgv = bg1[n];
#pragma unroll
      for (int r = 0; r < 4; ++r)
        Ht[(wr * 32 + mi * 16 + lqd * 4 + r) * 264 + n] =
            f2bu(fmaxf(acc[mi][ni][r] + bgv, 0.0f));
    }
  __syncthreads();

#pragma unroll
  for (int mi = 0; mi < 2; ++mi)
#pragma unroll
    for (int ni = 0; ni < 8; ++ni) acc[mi][ni] = (f32x4){0.f, 0.f, 0.f, 0.f};

  // ---- GEMM3: logits = t @ Wg2^T + bg2; softmax over 16 rows; attn + rp ----
  GEMM_LOOP(wg2t)
#undef GEMM_LOOP

#pragma unroll
  for (int mi = 0; mi < 2; ++mi) {
    int mtile = m0 + wr * 32 + mi * 16;
    int qrow = mtile >> 4;
#pragma unroll
    for (int ni = 0; ni < 8; ++ni) {
      int n = wc * 128 + ni * 16 + lm;
      float bv = bg2[n];
      float l0 = acc[mi][ni][0] + bv, l1 = acc[mi][ni][1] + bv;
      float l2 = acc[mi][ni][2] + bv, l3 = acc[mi][ni][3] + bv;
      float mx = fmaxf(fmaxf(l0, l1), fmaxf(l2, l3));
      mx = fmaxf(mx, __shfl_xor(mx, 16, 64));
      mx = fmaxf(mx, __shfl_xor(mx, 32, 64));
      float ev[4];
      ev[0] = __expf((l0 - mx) * 0.0625f);
      ev[1] = __expf((l1 - mx) * 0.0625f);
      ev[2] = __expf((l2 - mx) * 0.0625f);
      ev[3] = __expf((l3 - mx) * 0.0625f);
      float s = ev[0] + ev[1] + ev[2] + ev[3];
      s += __shfl_xor(s, 16, 64);
      s += __shfl_xor(s, 32, 64);
      float inv = 1.0f / s;
      float rp = 0.0f;
#pragma unroll
      for (int r = 0; r < 4; ++r) {
        size_t m = (size_t)(mtile + lqd * 4 + r);
        float a = ev[r] * inv;
        attn_out[m * 256 + n] = a;
        rp += a * b2f(vpbuf[m * 256 + n]);
      }
      rp += __shfl_xor(rp, 16, 64);
      rp += __shfl_xor(rp, 32, 64);
      if (lqd == 0) respre[(size_t)qrow * 256 + n] = f2b(rp);
    }
  }
}

// ---------------- tiled bf16 MFMA GEMM: C = A[M,K] @ BT[N,K]^T ----------------
template <int EPI, typename AT, typename CT>
__global__ __launch_bounds__(256) void gemm_bt(
    const AT* __restrict__ A, const bf16* __restrict__ BT,
    const float* __restrict__ bias, CT* __restrict__ C,
    int M, int N, int K,
    const float* __restrict__ resid) {
  __shared__ __align__(16) unsigned short As[128 * 72];
  __shared__ __align__(16) unsigned short Bs[128 * 72];

  int ntn = N >> 7;
  int bx = blockIdx.x % ntn, by = blockIdx.x / ntn;
  int m0 = by * 128, n0 = bx * 128;
  int tid = threadIdx.x;
  int wave = tid >> 6, lane = tid & 63;
  int wr = wave >> 1, wc = wave & 1;
  int lm = lane & 15, lqd = lane >> 4;

  f32x4 acc[4][4] = {};

  for (int k0 = 0; k0 < K; k0 += 64) {
#pragma unroll
    for (int i = 0; i < 4; ++i) {
      int flat = i * 256 + tid;
      int row = flat >> 3;
      int u = flat & 7;
      if constexpr (sizeof(AT) == 4) {
        const float* ap = (const float*)A + (size_t)(m0 + row) * K + k0 + u * 8;
        float4 a0 = *reinterpret_cast<const float4*>(ap);
        float4 a1 = *reinterpret_cast<const float4*>(ap + 4);
        unsigned short* dst = &As[row * 72 + u * 8];
        dst[0] = f2bu(a0.x); dst[1] = f2bu(a0.y); dst[2] = f2bu(a0.z); dst[3] = f2bu(a0.w);
        dst[4] = f2bu(a1.x); dst[5] = f2bu(a1.y); dst[6] = f2bu(a1.z); dst[7] = f2bu(a1.w);
      } else {
        int4 av = *reinterpret_cast<const int4*>((const bf16*)A + (size_t)(m0 + row) * K + k0 + u * 8);
        *reinterpret_cast<int4*>(&As[row * 72 + u * 8]) = av;
      }
      int4 bv = *reinterpret_cast<const int4*>(BT + (size_t)(n0 + row) * K + k0 + u * 8);
      *reinterpret_cast<int4*>(&Bs[row * 72 + u * 8]) = bv;
    }
    __syncthreads();
#pragma unroll
    for (int ks = 0; ks < 2; ++ks) {
      bf16x8 af[4], bfr[4];
#pragma unroll
      for (int mi = 0; mi < 4; ++mi)
        af[mi] = *reinterpret_cast<const bf16x8*>(
            &As[(wr * 64 + mi * 16 + lm) * 72 + ks * 32 + lqd * 8]);
#pragma unroll
      for (int ni = 0; ni < 4; ++ni)
        bfr[ni] = *reinterpret_cast<const bf16x8*>(
            &Bs[(wc * 64 + ni * 16 + lm) * 72 + ks * 32 + lqd * 8]);
#pragma unroll
      for (int mi = 0; mi < 4; ++mi)
#pragma unroll
        for (int ni = 0; ni < 4; ++ni)
          acc[mi][ni] = __builtin_amdgcn_mfma_f32_16x16x32_bf16(af[mi], bfr[ni],
                                                                acc[mi][ni], 0, 0, 0);
    }
    __syncthreads();
  }

#pragma unroll
  for (int mi = 0; mi < 4; ++mi) {
    int mbase = m0 + wr * 64 + mi * 16;
#pragma unroll
    for (int ni = 0; ni < 4; ++ni) {
      int n = n0 + wc * 64 + ni * 16 + lm;
      float bv = bias ? bias[n] : 0.0f;
#pragma unroll
      for (int r = 0; r < 4; ++r) {
        size_t m = (size_t)(mbase + lqd * 4 + r);
        float v = acc[mi][ni][r] + bv;
        if constexpr (EPI == 4) {
          v += resid[m * (size_t)N + n];
          C[m * (size_t)N + n] = v;
        } else {
          C[m * (size_t)N + n] = f2b(v);
        }
      }
    }
  }
}

// ---------------- launcher ----------------
extern "C" void kernel_launch(void* const* d_in, const int* in_sizes, int n_in,
                              void* d_out, int out_size, void* d_ws, size_t ws_size,
                              hipStream_t stream) {
  const float* xyz = (const float*)d_in[0];
  const float* feat = (const float*)d_in[1];
  const float* W1 = (const float*)d_in[2];
  const float* b1 = (const float*)d_in[3];
  const float* W2 = (const float*)d_in[4];
  const float* b2 = (const float*)d_in[5];
  const float* Wd1 = (const float*)d_in[6];
  const float* bd1 = (const float*)d_in[7];
  const float* Wd2 = (const float*)d_in[8];
  const float* bd2 = (const float*)d_in[9];
  const float* Wg1 = (const float*)d_in[10];
  const float* bg1 = (const float*)d_in[11];
  const float* Wg2 = (const float*)d_in[12];
  const float* bg2 = (const float*)d_in[13];
  const float* Wq = (const float*)d_in[14];
  const float* Wk = (const float*)d_in[15];
  const float* Wv = (const float*)d_in[16];

  constexpr size_t XBUF = 0;
  constexpr size_t QBUF = 8388608;
  constexpr size_t KBUF = 16777216;
  constexpr size_t VBUF = 25165824;
  constexpr size_t RESPRE = 33554432;
  constexpr size_t GIDX = 41943040;
  constexpr size_t W1T = 42991616;
  constexpr size_t W2T = 43253760;
  constexpr size_t WQT = 43515904;
  constexpr size_t WKT = 43646976;
  constexpr size_t WVT = 43778048;
  constexpr size_t WD2T = 43909120;
  constexpr size_t WG1T = 44040192;
  constexpr size_t WG2T = 44171264;
  constexpr size_t HIDDEN = 44302336;          // [262144,256] bf16
  constexpr size_t VPBUF = 178520064;          // [262144,256] bf16 (knn scratch first)
  constexpr size_t WS_NEEDED = 446955520;
  if (ws_size < WS_NEEDED) return;

  char* ws = (char*)d_ws;
  bf16* xbuf = (bf16*)(ws + XBUF);
  bf16* qbuf = (bf16*)(ws + QBUF);
  bf16* kbuf = (bf16*)(ws + KBUF);
  bf16* vbuf = (bf16*)(ws + VBUF);
  bf16* respre = (bf16*)(ws + RESPRE);
  int* gidx = (int*)(ws + GIDX);
  bf16* w1t = (bf16*)(ws + W1T);
  bf16* w2t = (bf16*)(ws + W2T);
  bf16* wqt = (bf16*)(ws + WQT);
  bf16* wkt = (bf16*)(ws + WKT);
  bf16* wvt = (bf16*)(ws + WVT);
  bf16* wd2t = (bf16*)(ws + WD2T);
  bf16* wg1t = (bf16*)(ws + WG1T);
  bf16* wg2t = (bf16*)(ws + WG2T);
  bf16* hidden = (bf16*)(ws + HIDDEN);
  bf16* vpbuf = (bf16*)(ws + VPBUF);

  // knn scratch lives in the VPBUF region (free until fused_pt; knn completes first)
  unsigned long long* knnkeys = (unsigned long long*)(ws + VPBUF);           // 64 MB
  float4* pts4 = (float4*)(ws + VPBUF + 67108864);                           // 256 KB

  float* res_out = (float*)d_out;
  float* attn_out = res_out + (size_t)16384 * 512;

  transpose_k<<<512, 256, 0, stream>>>(W1, w1t, 512, 256);
  transpose_k<<<512, 256, 0, stream>>>(W2, w2t, 256, 512);
  transpose_k<<<256, 256, 0, stream>>>(Wq, wqt, 256, 256);
  transpose_k<<<256, 256, 0, stream>>>(Wk, wkt, 256, 256);
  transpose_k<<<256, 256, 0, stream>>>(Wv, wvt, 256, 256);
  transpose_k<<<256, 256, 0, stream>>>(Wd2, wd2t, 256, 256);
  transpose_k<<<256, 256, 0, stream>>>(Wg1, wg1t, 256, 256);
  transpose_k<<<256, 256, 0, stream>>>(Wg2, wg2t, 256, 256);

  pack_pts<<<64, 256, 0, stream>>>(xyz, pts4);
  knn_partial<<<2048, 256, 0, stream>>>(pts4, knnkeys);
  knn_merge<<<64, 256, 0, stream>>>(knnkeys, gidx);

  gemm_bt<0, float, bf16><<<128 * 2, 256, 0, stream>>>(
      feat, w1t, b1, xbuf, 16384, 256, 512, nullptr);
  gemm_bt<0, bf16, bf16><<<128 * 2, 256, 0, stream>>>(
      xbuf, wqt, nullptr, qbuf, 16384, 256, 256, nullptr);
  gemm_bt<0, bf16, bf16><<<128 * 2, 256, 0, stream>>>(
      xbuf, wkt, nullptr, kbuf, 16384, 256, 256, nullptr);
  gemm_bt<0, bf16, bf16><<<128 * 2, 256, 0, stream>>>(
      xbuf, wvt, nullptr, vbuf, 16384, 256, 256, nullptr);

  hidden_kernel<<<16384, 256, 0, stream>>>(xyz, gidx, Wd1, bd1, hidden);

  fused_pt<<<4096, 256, 0, stream>>>(hidden, wd2t, bd2, wg1t, bg1, wg2t, bg2,
                                     qbuf, kbuf, vbuf, gidx, vpbuf, attn_out, respre);

  gemm_bt<4, bf16, float><<<128 * 4, 256, 0, stream>>>(
      respre, w2t, b2, res_out, 16384, 512, 256, feat);
}

// Round 6
// 1029.843 us; speedup vs baseline: 1.2746x; 1.2746x over previous
//
#include <hip/hip_runtime.h>
#include <hip/hip_bf16.h>
#include <stdint.h>

typedef __hip_bfloat16 bf16;
typedef float f32x4 __attribute__((ext_vector_type(4)));
typedef __bf16 bf16x8 __attribute__((ext_vector_type(8)));

__device__ __forceinline__ float b2f(bf16 v) { return __bfloat162float(v); }
__device__ __forceinline__ bf16 f2b(float v) { return __float2bfloat16(v); }
__device__ __forceinline__ unsigned short f2bu(float f) {
  unsigned u = __float_as_uint(f);
  unsigned r = u + 0x7fffu + ((u >> 16) & 1u);
  return (unsigned short)(r >> 16);
}

// B=4, N=4096, D_POINTS=512, D_MODEL=256, K=16

// compare-exchange on u64 keys: min -> a, max -> b (1 cmp + 4 cndmask, no arrays)
#define CE64(a, b)                                            \
  do {                                                        \
    bool c_ = (b) < (a);                                      \
    unsigned long long lo_ = c_ ? (b) : (a);                  \
    unsigned long long hi_ = c_ ? (a) : (b);                  \
    (a) = lo_; (b) = hi_;                                     \
  } while (0)

// ascending / descending compare-exchange, and min-only (3 ops)
#define CEA(x, y) CE64(x, y)
#define CED(x, y) CE64(y, x)
#define MIN64(x, y)                                           \
  do {                                                        \
    (x) = (y) < (x) ? (y) : (x);                              \
  } while (0)

// ---------------- pack xyz -> float4(x,y,z,sq) ----------------
__global__ __launch_bounds__(256) void pack_pts(const float* __restrict__ xyz,
                                                float4* __restrict__ pts) {
  int i = blockIdx.x * 256 + threadIdx.x;   // 0..16383
  float x = xyz[i * 3 + 0];
  float y = xyz[i * 3 + 1];
  float z = xyz[i * 3 + 2];
  float sq = __fadd_rn(__fadd_rn(__fmul_rn(x, x), __fmul_rn(y, y)), __fmul_rn(z, z));
  pts[i] = make_float4(x, y, z, sq);
}

// ---------------- knn partial: 2048 blocks; block=(group g, range r) ----------------
__global__ __launch_bounds__(256) void knn_partial(const float4* __restrict__ pts,
                                                   unsigned long long* __restrict__ keys) {
  __shared__ __align__(16) float4 cs[512];
  __shared__ __align__(16) float4 qs[64];

  int tid = threadIdx.x;
  int g = blockIdx.x >> 3;          // query group 0..255 (64 queries each)
  int r = blockIdx.x & 7;           // candidate range (512 candidates)
  int batch = g >> 6;
  const float4* pp = pts + batch * 4096;
  int cb = r * 512;

  cs[tid] = pp[cb + tid];
  cs[256 + tid] = pp[cb + 256 + tid];
  if (tid < 64) qs[tid] = pp[(g & 63) * 64 + tid];
  __syncthreads();

  int wave = tid >> 6, lq = tid & 63;
  float4 Q = qs[lq];
  int mbase = cb + wave * 128;

  unsigned long long a[16];
#pragma unroll
  for (int i = 0; i < 16; ++i) a[i] = ~0ull;

#pragma unroll 2
  for (int tb = 0; tb < 16; ++tb) {
    unsigned long long c[8];
#pragma unroll
    for (int j = 0; j < 8; ++j) {
      float4 P = cs[wave * 128 + tb * 8 + j];
      float dot = __fadd_rn(__fadd_rn(__fmul_rn(Q.x, P.x), __fmul_rn(Q.y, P.y)),
                            __fmul_rn(Q.z, P.z));
      float d = __fsub_rn(__fadd_rn(Q.w, P.w), __fmul_rn(2.0f, dot));
      unsigned u = __float_as_uint(d);
      u ^= (unsigned)((int)u >> 31) | 0x80000000u;   // monotonic float bits
      c[j] = ((unsigned long long)u << 32) | (unsigned)(mbase + tb * 8 + j);
    }

    // bitonic sort8 ascending: c[0] <= ... <= c[7]
    CEA(c[0], c[1]); CED(c[2], c[3]); CEA(c[4], c[5]); CED(c[6], c[7]);
    CEA(c[0], c[2]); CEA(c[1], c[3]); CED(c[4], c[6]); CED(c[5], c[7]);
    CEA(c[0], c[1]); CEA(c[2], c[3]); CED(c[4], c[5]); CED(c[6], c[7]);
    CEA(c[0], c[4]); CEA(c[1], c[5]); CEA(c[2], c[6]); CEA(c[3], c[7]);
    CEA(c[0], c[2]); CEA(c[1], c[3]); CEA(c[4], c[6]); CEA(c[5], c[7]);
    CEA(c[0], c[1]); CEA(c[2], c[3]); CEA(c[4], c[5]); CEA(c[6], c[7]);

    // lower-16 of merge(a asc16, c asc8): positions 8..15 take min with reversed c
    MIN64(a[8],  c[7]); MIN64(a[9],  c[6]); MIN64(a[10], c[5]); MIN64(a[11], c[4]);
    MIN64(a[12], c[3]); MIN64(a[13], c[2]); MIN64(a[14], c[1]); MIN64(a[15], c[0]);

    // bitonic clean-16 (result is bitonic): distances 8,4,2,1, all ascending
    CEA(a[0], a[8]);  CEA(a[1], a[9]);  CEA(a[2], a[10]); CEA(a[3], a[11]);
    CEA(a[4], a[12]); CEA(a[5], a[13]); CEA(a[6], a[14]); CEA(a[7], a[15]);
    CEA(a[0], a[4]);  CEA(a[1], a[5]);  CEA(a[2], a[6]);  CEA(a[3], a[7]);
    CEA(a[8], a[12]); CEA(a[9], a[13]); CEA(a[10], a[14]); CEA(a[11], a[15]);
    CEA(a[0], a[2]);  CEA(a[1], a[3]);  CEA(a[4], a[6]);  CEA(a[5], a[7]);
    CEA(a[8], a[10]); CEA(a[9], a[11]); CEA(a[12], a[14]); CEA(a[13], a[15]);
    CEA(a[0], a[1]);  CEA(a[2], a[3]);  CEA(a[4], a[5]);  CEA(a[6], a[7]);
    CEA(a[8], a[9]);  CEA(a[10], a[11]); CEA(a[12], a[13]); CEA(a[14], a[15]);
  }

  int rw = r * 4 + wave;            // 0..31
  int q = g * 64 + lq;
  unsigned long long* o = keys + (size_t)(rw * 16) * 16384 + q;
#pragma unroll
  for (int j = 0; j < 16; ++j) o[(size_t)j * 16384] = a[j];
}

// ---------------- knn merge: 32 sorted lists -> final 16, thread per query ----------------
__global__ __launch_bounds__(256) void knn_merge(const unsigned long long* __restrict__ keys,
                                                 int* __restrict__ gidx) {
  int q = blockIdx.x * 256 + threadIdx.x;   // 0..16383
  const unsigned long long* kq = keys + q;

#define LOADL(rw)                                   \
  unsigned long long l0 = kq[((rw) * 16 + 0) * 16384],  l1 = kq[((rw) * 16 + 1) * 16384],  \
                     l2 = kq[((rw) * 16 + 2) * 16384],  l3 = kq[((rw) * 16 + 3) * 16384],  \
                     l4 = kq[((rw) * 16 + 4) * 16384],  l5 = kq[((rw) * 16 + 5) * 16384],  \
                     l6 = kq[((rw) * 16 + 6) * 16384],  l7 = kq[((rw) * 16 + 7) * 16384],  \
                     l8 = kq[((rw) * 16 + 8) * 16384],  l9 = kq[((rw) * 16 + 9) * 16384],  \
                     l10 = kq[((rw) * 16 + 10) * 16384], l11 = kq[((rw) * 16 + 11) * 16384], \
                     l12 = kq[((rw) * 16 + 12) * 16384], l13 = kq[((rw) * 16 + 13) * 16384], \
                     l14 = kq[((rw) * 16 + 14) * 16384], l15 = kq[((rw) * 16 + 15) * 16384]

  unsigned long long a0 = kq[0],           a1 = kq[16384],      a2 = kq[2 * 16384],
                     a3 = kq[3 * 16384],   a4 = kq[4 * 16384],  a5 = kq[5 * 16384],
                     a6 = kq[6 * 16384],   a7 = kq[7 * 16384],  a8 = kq[8 * 16384],
                     a9 = kq[9 * 16384],   a10 = kq[10 * 16384], a11 = kq[11 * 16384],
                     a12 = kq[12 * 16384], a13 = kq[13 * 16384], a14 = kq[14 * 16384],
                     a15 = kq[15 * 16384];

  for (int rw = 1; rw < 32; ++rw) {
    LOADL(rw);
    // lower half of bitonic merge of (a asc ++ l desc): min(a_i, l_{15-i}) -> bitonic
    a0 = a0 < l15 ? a0 : l15;   a1 = a1 < l14 ? a1 : l14;
    a2 = a2 < l13 ? a2 : l13;   a3 = a3 < l12 ? a3 : l12;
    a4 = a4 < l11 ? a4 : l11;   a5 = a5 < l10 ? a5 : l10;
    a6 = a6 < l9 ? a6 : l9;     a7 = a7 < l8 ? a7 : l8;
    a8 = a8 < l7 ? a8 : l7;     a9 = a9 < l6 ? a9 : l6;
    a10 = a10 < l5 ? a10 : l5;  a11 = a11 < l4 ? a11 : l4;
    a12 = a12 < l3 ? a12 : l3;  a13 = a13 < l2 ? a13 : l2;
    a14 = a14 < l1 ? a14 : l1;  a15 = a15 < l0 ? a15 : l0;
    // bitonic sort of 16 bitonic elements: stages 8,4,2,1
    CE64(a0, a8);  CE64(a1, a9);  CE64(a2, a10); CE64(a3, a11);
    CE64(a4, a12); CE64(a5, a13); CE64(a6, a14); CE64(a7, a15);
    CE64(a0, a4);  CE64(a1, a5);  CE64(a2, a6);  CE64(a3, a7);
    CE64(a8, a12); CE64(a9, a13); CE64(a10, a14); CE64(a11, a15);
    CE64(a0, a2);  CE64(a1, a3);  CE64(a4, a6);  CE64(a5, a7);
    CE64(a8, a10); CE64(a9, a11); CE64(a12, a14); CE64(a13, a15);
    CE64(a0, a1);  CE64(a2, a3);  CE64(a4, a5);  CE64(a6, a7);
    CE64(a8, a9);  CE64(a10, a11); CE64(a12, a13); CE64(a14, a15);
  }
#undef LOADL

  int base = (q >> 12) << 12;   // batch*4096
  int* o = gidx + (size_t)q * 16;
  o[0] = base + (int)(a0 & 0xffffffffu);   o[1] = base + (int)(a1 & 0xffffffffu);
  o[2] = base + (int)(a2 & 0xffffffffu);   o[3] = base + (int)(a3 & 0xffffffffu);
  o[4] = base + (int)(a4 & 0xffffffffu);   o[5] = base + (int)(a5 & 0xffffffffu);
  o[6] = base + (int)(a6 & 0xffffffffu);   o[7] = base + (int)(a7 & 0xffffffffu);
  o[8] = base + (int)(a8 & 0xffffffffu);   o[9] = base + (int)(a9 & 0xffffffffu);
  o[10] = base + (int)(a10 & 0xffffffffu); o[11] = base + (int)(a11 & 0xffffffffu);
  o[12] = base + (int)(a12 & 0xffffffffu); o[13] = base + (int)(a13 & 0xffffffffu);
  o[14] = base + (int)(a14 & 0xffffffffu); o[15] = base + (int)(a15 & 0xffffffffu);
}

// ---------------- weight transpose + f32->bf16 ----------------
__global__ __launch_bounds__(256) void transpose_k(const float* __restrict__ src,
                                                   bf16* __restrict__ dst,
                                                   int R, int C) {
  int i = blockIdx.x * 256 + threadIdx.x;
  if (i < R * C) {
    int r = i / C, c = i - r * C;
    dst[c * R + r] = f2b(src[i]);
  }
}

// ---------------- hidden = relu(rel @ Wd1 + bd1) ----------------
__global__ __launch_bounds__(256) void hidden_kernel(const float* __restrict__ xyz,
                                                     const int* __restrict__ gidx,
                                                     const float* __restrict__ Wd1,
                                                     const float* __restrict__ bd1,
                                                     bf16* __restrict__ hidden) {
  __shared__ float rel[16][3];
  int q = blockIdx.x;
  int tid = threadIdx.x;
  if (tid < 16) {
    int g = gidx[q * 16 + tid];
    rel[tid][0] = xyz[(size_t)q * 3 + 0] - xyz[(size_t)g * 3 + 0];
    rel[tid][1] = xyz[(size_t)q * 3 + 1] - xyz[(size_t)g * 3 + 1];
    rel[tid][2] = xyz[(size_t)q * 3 + 2] - xyz[(size_t)g * 3 + 2];
  }
  __syncthreads();
  float w0 = Wd1[tid], w1 = Wd1[256 + tid], w2 = Wd1[512 + tid];
  float bb = bd1[tid];
#pragma unroll
  for (int j = 0; j < 16; ++j) {
    float v = rel[j][0] * w0 + rel[j][1] * w1 + rel[j][2] * w2 + bb;
    v = fmaxf(v, 0.0f);
    hidden[((size_t)q * 16 + j) * 256 + tid] = f2b(v);
  }
}

// ---------------- fused pos/attn chain ----------------
// Per block: 64 rows (4 queries), A-tile LDS-resident (33.8 KB only).
// B (weights, 128 KB each, L2-resident) is loaded per-lane DIRECTLY from
// global into MFMA fragments — no LDS staging, no k-loop barriers.
// Only 6 barriers/block (around the two Ht rewrites).
// vp round-trips through global (vpbuf) to keep VGPR below spill threshold.
__global__ __launch_bounds__(256, 3) void fused_pt(
    const bf16* __restrict__ hidden,   // [262144,256] relu(rel@Wd1+bd1)
    const bf16* __restrict__ wd2t, const float* __restrict__ bd2,
    const bf16* __restrict__ wg1t, const float* __restrict__ bg1,
    const bf16* __restrict__ wg2t, const float* __restrict__ bg2,
    const bf16* __restrict__ qbuf, const bf16* __restrict__ kbuf,
    const bf16* __restrict__ vbuf, const int* __restrict__ gidx,
    bf16* __restrict__ vpbuf,          // [262144,256] v+pos round trip
    float* __restrict__ attn_out,      // [262144,256] f32
    bf16* __restrict__ respre) {       // [16384,256]
  __shared__ __align__(16) unsigned short Ht[64 * 264];   // A tile, stride 264

  int m0 = blockIdx.x * 64;
  int tid = threadIdx.x;
  int wave = tid >> 6, lane = tid & 63;
  int wr = wave >> 1, wc = wave & 1;          // 2x2 waves: 32-row x 128-col tiles
  int lm = lane & 15, lqd = lane >> 4;

  // stage hidden tile: 64x256 bf16 = 2048 int4, 8 per thread
#pragma unroll
  for (int i = 0; i < 8; ++i) {
    int flat = i * 256 + tid;
    int row = flat >> 5;          // 32 int4 per row
    int u = flat & 31;
    int4 hv = *reinterpret_cast<const int4*>(hidden + (size_t)(m0 + row) * 256 + u * 8);
    *reinterpret_cast<int4*>(&Ht[row * 264 + u * 8]) = hv;
  }
  __syncthreads();

  f32x4 acc[2][8];
#pragma unroll
  for (int mi = 0; mi < 2; ++mi)
#pragma unroll
    for (int ni = 0; ni < 8; ++ni) acc[mi][ni] = (f32x4){0.f, 0.f, 0.f, 0.f};

  // per-lane base offset into BT for this wave's 128-col slice
  const size_t boff = (size_t)(wc * 128 + lm) * 256 + lqd * 8;

  // GEMM over K=256 in 32-wide steps; A from LDS (own rows), B direct from
  // global (L2-hot weights). No barriers inside the loop.
#define GEMM_LOOP(BTP)                                                          \
  _Pragma("unroll 2")                                                           \
  for (int ks = 0; ks < 8; ++ks) {                                              \
    bf16x8 af[2], bfr[8];                                                       \
    _Pragma("unroll")                                                           \
    for (int ni = 0; ni < 8; ++ni)                                              \
      bfr[ni] = *reinterpret_cast<const bf16x8*>(                               \
          (BTP) + boff + (size_t)ni * 16 * 256 + ks * 32);                      \
    _Pragma("unroll")                                                           \
    for (int mi = 0; mi < 2; ++mi)                                              \
      af[mi] = *reinterpret_cast<const bf16x8*>(                                \
          &Ht[(wr * 32 + mi * 16 + lm) * 264 + ks * 32 + lqd * 8]);             \
    _Pragma("unroll")                                                           \
    for (int mi = 0; mi < 2; ++mi)                                              \
      _Pragma("unroll")                                                         \
      for (int ni = 0; ni < 8; ++ni)                                            \
        acc[mi][ni] = __builtin_amdgcn_mfma_f32_16x16x32_bf16(                  \
            af[mi], bfr[ni], acc[mi][ni], 0, 0, 0);                             \
  }

  // ---- GEMM1: pos = hidden @ Wd2^T ----
  GEMM_LOOP(wd2t)

  // ---- epilogue 1: h = q - k + pos -> Ht;  vp = v + pos -> vpbuf (global) ----
  __syncthreads();
#pragma unroll
  for (int mi = 0; mi < 2; ++mi) {
    int mtile = m0 + wr * 32 + mi * 16;    // 16 rows = one query
    int qrow = mtile >> 4;
    int gi[4];
#pragma unroll
    for (int r = 0; r < 4; ++r) gi[r] = gidx[mtile + lqd * 4 + r];
#pragma unroll
    for (int ni = 0; ni < 8; ++ni) {
      int n = wc * 128 + ni * 16 + lm;
      float qv = b2f(qbuf[(size_t)qrow * 256 + n]);
      float bdv = bd2[n];
#pragma unroll
      for (int r = 0; r < 4; ++r) {
        float pos = acc[mi][ni][r] + bdv;
        float kv = b2f(kbuf[(size_t)gi[r] * 256 + n]);
        float vv = b2f(vbuf[(size_t)gi[r] * 256 + n]);
        size_t m = (size_t)(mtile + lqd * 4 + r);
        Ht[(wr * 32 + mi * 16 + lqd * 4 + r) * 264 + n] = f2bu(qv - kv + pos);
        vpbuf[m * 256 + n] = f2b(vv + pos);
      }
    }
  }
  __syncthreads();

#pragma unroll
  for (int mi = 0; mi < 2; ++mi)
#pragma unroll
    for (int ni = 0; ni < 8; ++ni) acc[mi][ni] = (f32x4){0.f, 0.f, 0.f, 0.f};

  // ---- GEMM2: t = relu(h @ Wg1^T + bg1) ----
  GEMM_LOOP(wg1t)

  __syncthreads();
#pragma unroll
  for (int mi = 0; mi < 2; ++mi)
#pragma unroll
    for (int ni = 0; ni < 8; ++ni) {
      int n = wc * 128 + ni * 16 + lm;
      float bgv = bg1[n];
#pragma unroll
      for (int r = 0; r < 4; ++r)
        Ht[(wr * 32 + mi * 16 + lqd * 4 + r) * 264 + n] =
            f2bu(fmaxf(acc[mi][ni][r] + bgv, 0.0f));
    }
  __syncthreads();

#pragma unroll
  for (int mi = 0; mi < 2; ++mi)
#pragma unroll
    for (int ni = 0; ni < 8; ++ni) acc[mi][ni] = (f32x4){0.f, 0.f, 0.f, 0.f};

  // ---- GEMM3: logits = t @ Wg2^T + bg2; softmax over 16 rows; attn + rp ----
  GEMM_LOOP(wg2t)
#undef GEMM_LOOP

#pragma unroll
  for (int mi = 0; mi < 2; ++mi) {
    int mtile = m0 + wr * 32 + mi * 16;
    int qrow = mtile >> 4;
#pragma unroll
    for (int ni = 0; ni < 8; ++ni) {
      int n = wc * 128 + ni * 16 + lm;
      float bv = bg2[n];
      float l0 = acc[mi][ni][0] + bv, l1 = acc[mi][ni][1] + bv;
      float l2 = acc[mi][ni][2] + bv, l3 = acc[mi][ni][3] + bv;
      float mx = fmaxf(fmaxf(l0, l1), fmaxf(l2, l3));
      mx = fmaxf(mx, __shfl_xor(mx, 16, 64));
      mx = fmaxf(mx, __shfl_xor(mx, 32, 64));
      float ev[4];
      ev[0] = __expf((l0 - mx) * 0.0625f);
      ev[1] = __expf((l1 - mx) * 0.0625f);
      ev[2] = __expf((l2 - mx) * 0.0625f);
      ev[3] = __expf((l3 - mx) * 0.0625f);
      float s = ev[0] + ev[1] + ev[2] + ev[3];
      s += __shfl_xor(s, 16, 64);
      s += __shfl_xor(s, 32, 64);
      float inv = 1.0f / s;
      float rp = 0.0f;
#pragma unroll
      for (int r = 0; r < 4; ++r) {
        size_t m = (size_t)(mtile + lqd * 4 + r);
        float a = ev[r] * inv;
        attn_out[m * 256 + n] = a;
        rp += a * b2f(vpbuf[m * 256 + n]);
      }
      rp += __shfl_xor(rp, 16, 64);
      rp += __shfl_xor(rp, 32, 64);
      if (lqd == 0) respre[(size_t)qrow * 256 + n] = f2b(rp);
    }
  }
}

// ---------------- tiled bf16 MFMA GEMM: C = A[M,K] @ BT[N,K]^T ----------------
template <int EPI, typename AT, typename CT>
__global__ __launch_bounds__(256) void gemm_bt(
    const AT* __restrict__ A, const bf16* __restrict__ BT,
    const float* __restrict__ bias, CT* __restrict__ C,
    int M, int N, int K,
    const float* __restrict__ resid) {
  __shared__ __align__(16) unsigned short As[128 * 72];
  __shared__ __align__(16) unsigned short Bs[128 * 72];

  int ntn = N >> 7;
  int bx = blockIdx.x % ntn, by = blockIdx.x / ntn;
  int m0 = by * 128, n0 = bx * 128;
  int tid = threadIdx.x;
  int wave = tid >> 6, lane = tid & 63;
  int wr = wave >> 1, wc = wave & 1;
  int lm = lane & 15, lqd = lane >> 4;

  f32x4 acc[4][4] = {};

  for (int k0 = 0; k0 < K; k0 += 64) {
#pragma unroll
    for (int i = 0; i < 4; ++i) {
      int flat = i * 256 + tid;
      int row = flat >> 3;
      int u = flat & 7;
      if constexpr (sizeof(AT) == 4) {
        const float* ap = (const float*)A + (size_t)(m0 + row) * K + k0 + u * 8;
        float4 a0 = *reinterpret_cast<const float4*>(ap);
        float4 a1 = *reinterpret_cast<const float4*>(ap + 4);
        unsigned short* dst = &As[row * 72 + u * 8];
        dst[0] = f2bu(a0.x); dst[1] = f2bu(a0.y); dst[2] = f2bu(a0.z); dst[3] = f2bu(a0.w);
        dst[4] = f2bu(a1.x); dst[5] = f2bu(a1.y); dst[6] = f2bu(a1.z); dst[7] = f2bu(a1.w);
      } else {
        int4 av = *reinterpret_cast<const int4*>((const bf16*)A + (size_t)(m0 + row) * K + k0 + u * 8);
        *reinterpret_cast<int4*>(&As[row * 72 + u * 8]) = av;
      }
      int4 bv = *reinterpret_cast<const int4*>(BT + (size_t)(n0 + row) * K + k0 + u * 8);
      *reinterpret_cast<int4*>(&Bs[row * 72 + u * 8]) = bv;
    }
    __syncthreads();
#pragma unroll
    for (int ks = 0; ks < 2; ++ks) {
      bf16x8 af[4], bfr[4];
#pragma unroll
      for (int mi = 0; mi < 4; ++mi)
        af[mi] = *reinterpret_cast<const bf16x8*>(
            &As[(wr * 64 + mi * 16 + lm) * 72 + ks * 32 + lqd * 8]);
#pragma unroll
      for (int ni = 0; ni < 4; ++ni)
        bfr[ni] = *reinterpret_cast<const bf16x8*>(
            &Bs[(wc * 64 + ni * 16 + lm) * 72 + ks * 32 + lqd * 8]);
#pragma unroll
      for (int mi = 0; mi < 4; ++mi)
#pragma unroll
        for (int ni = 0; ni < 4; ++ni)
          acc[mi][ni] = __builtin_amdgcn_mfma_f32_16x16x32_bf16(af[mi], bfr[ni],
                                                                acc[mi][ni], 0, 0, 0);
    }
    __syncthreads();
  }

#pragma unroll
  for (int mi = 0; mi < 4; ++mi) {
    int mbase = m0 + wr * 64 + mi * 16;
#pragma unroll
    for (int ni = 0; ni < 4; ++ni) {
      int n = n0 + wc * 64 + ni * 16 + lm;
      float bv = bias ? bias[n] : 0.0f;
#pragma unroll
      for (int r = 0; r < 4; ++r) {
        size_t m = (size_t)(mbase + lqd * 4 + r);
        float v = acc[mi][ni][r] + bv;
        if constexpr (EPI == 4) {
          v += resid[m * (size_t)N + n];
          C[m * (size_t)N + n] = v;
        } else {
          C[m * (size_t)N + n] = f2b(v);
        }
      }
    }
  }
}

// ---------------- launcher ----------------
extern "C" void kernel_launch(void* const* d_in, const int* in_sizes, int n_in,
                              void* d_out, int out_size, void* d_ws, size_t ws_size,
                              hipStream_t stream) {
  const float* xyz = (const float*)d_in[0];
  const float* feat = (const float*)d_in[1];
  const float* W1 = (const float*)d_in[2];
  const float* b1 = (const float*)d_in[3];
  const float* W2 = (const float*)d_in[4];
  const float* b2 = (const float*)d_in[5];
  const float* Wd1 = (const float*)d_in[6];
  const float* bd1 = (const float*)d_in[7];
  const float* Wd2 = (const float*)d_in[8];
  const float* bd2 = (const float*)d_in[9];
  const float* Wg1 = (const float*)d_in[10];
  const float* bg1 = (const float*)d_in[11];
  const float* Wg2 = (const float*)d_in[12];
  const float* bg2 = (const float*)d_in[13];
  const float* Wq = (const float*)d_in[14];
  const float* Wk = (const float*)d_in[15];
  const float* Wv = (const float*)d_in[16];

  constexpr size_t XBUF = 0;
  constexpr size_t QBUF = 8388608;
  constexpr size_t KBUF = 16777216;
  constexpr size_t VBUF = 25165824;
  constexpr size_t RESPRE = 33554432;
  constexpr size_t GIDX = 41943040;
  constexpr size_t W1T = 42991616;
  constexpr size_t W2T = 43253760;
  constexpr size_t WQT = 43515904;
  constexpr size_t WKT = 43646976;
  constexpr size_t WVT = 43778048;
  constexpr size_t WD2T = 43909120;
  constexpr size_t WG1T = 44040192;
  constexpr size_t WG2T = 44171264;
  constexpr size_t HIDDEN = 44302336;          // [262144,256] bf16
  constexpr size_t VPBUF = 178520064;          // [262144,256] bf16 (knn scratch first)
  constexpr size_t WS_NEEDED = 446955520;
  if (ws_size < WS_NEEDED) return;

  char* ws = (char*)d_ws;
  bf16* xbuf = (bf16*)(ws + XBUF);
  bf16* qbuf = (bf16*)(ws + QBUF);
  bf16* kbuf = (bf16*)(ws + KBUF);
  bf16* vbuf = (bf16*)(ws + VBUF);
  bf16* respre = (bf16*)(ws + RESPRE);
  int* gidx = (int*)(ws + GIDX);
  bf16* w1t = (bf16*)(ws + W1T);
  bf16* w2t = (bf16*)(ws + W2T);
  bf16* wqt = (bf16*)(ws + WQT);
  bf16* wkt = (bf16*)(ws + WKT);
  bf16* wvt = (bf16*)(ws + WVT);
  bf16* wd2t = (bf16*)(ws + WD2T);
  bf16* wg1t = (bf16*)(ws + WG1T);
  bf16* wg2t = (bf16*)(ws + WG2T);
  bf16* hidden = (bf16*)(ws + HIDDEN);
  bf16* vpbuf = (bf16*)(ws + VPBUF);

  // knn scratch lives in the VPBUF region (free until fused_pt; knn completes first)
  unsigned long long* knnkeys = (unsigned long long*)(ws + VPBUF);           // 64 MB
  float4* pts4 = (float4*)(ws + VPBUF + 67108864);                           // 256 KB

  float* res_out = (float*)d_out;
  float* attn_out = res_out + (size_t)16384 * 512;

  transpose_k<<<512, 256, 0, stream>>>(W1, w1t, 512, 256);
  transpose_k<<<512, 256, 0, stream>>>(W2, w2t, 256, 512);
  transpose_k<<<256, 256, 0, stream>>>(Wq, wqt, 256, 256);
  transpose_k<<<256, 256, 0, stream>>>(Wk, wkt, 256, 256);
  transpose_k<<<256, 256, 0, stream>>>(Wv, wvt, 256, 256);
  transpose_k<<<256, 256, 0, stream>>>(Wd2, wd2t, 256, 256);
  transpose_k<<<256, 256, 0, stream>>>(Wg1, wg1t, 256, 256);
  transpose_k<<<256, 256, 0, stream>>>(Wg2, wg2t, 256, 256);

  pack_pts<<<64, 256, 0, stream>>>(xyz, pts4);
  knn_partial<<<2048, 256, 0, stream>>>(pts4, knnkeys);
  knn_merge<<<64, 256, 0, stream>>>(knnkeys, gidx);

  gemm_bt<0, float, bf16><<<128 * 2, 256, 0, stream>>>(
      feat, w1t, b1, xbuf, 16384, 256, 512, nullptr);
  gemm_bt<0, bf16, bf16><<<128 * 2, 256, 0, stream>>>(
      xbuf, wqt, nullptr, qbuf, 16384, 256, 256, nullptr);
  gemm_bt<0, bf16, bf16><<<128 * 2, 256, 0, stream>>>(
      xbuf, wkt, nullptr, kbuf, 16384, 256, 256, nullptr);
  gemm_bt<0, bf16, bf16><<<128 * 2, 256, 0, stream>>>(
      xbuf, wvt, nullptr, vbuf, 16384, 256, 256, nullptr);

  hidden_kernel<<<16384, 256, 0, stream>>>(xyz, gidx, Wd1, bd1, hidden);

  fused_pt<<<4096, 256, 0, stream>>>(hidden, wd2t, bd2, wg1t, bg1, wg2t, bg2,
                                     qbuf, kbuf, vbuf, gidx, vpbuf, attn_out, respre);

  gemm_bt<4, bf16, float><<<128 * 4, 256, 0, stream>>>(
      respre, w2t, b2, res_out, 16384, 512, 256, feat);
}